// Round 3
// baseline (587.366 us; speedup 1.0000x reference)
//
#include <hip/hip_runtime.h>
#include <hip/hip_cooperative_groups.h>

namespace cg = cooperative_groups;

typedef unsigned int uint;

#define VOCAB 32000
#define NSLOT 8

// ws float offsets. Poison 0xAA = -3.03e-13f is numerically zero for all
// accumulations (w1/w2/uacc/rsum accumulate straight onto it; untouched w
// bins contribute ~1e-10 to the o-GEMV). P0/P1/P2 are fully overwritten.
#define OFF_UACC0 0          // NSLOT x 16 x 128
#define OFF_RSUM0 16384      // NSLOT x 16
#define OFF_UACC1 16512
#define OFF_RSUM1 32896      // ends 33024
#define OFF_P0    33024      // P_h[v*16+b] = C_h[v].u_h[b], 32000*16 floats
#define OFF_P1    545024
#define OFF_P2    1057024
#define OFF_W1    1569024    // w[v*16+b] = sum of exp(logit) over (m,s) with st==v
#define OFF_W2    2081024    // ends 2593024 (~10.4 MB)

// ---- dense P pass: chunk cb covers vocab rows [cb*64, cb*64+64) -----------
__device__ __forceinline__ void dense_gemv64(const float* __restrict__ Cr,
                                             float* __restrict__ Pout,
                                             const float4 (*us4)[33],
                                             int cb, int tid) {
    int wave = tid >> 6, lane = tid & 63;
    int b  = lane & 15;
    int rl = lane >> 4;
    int vb = cb * 64 + wave * 16 + rl * 4;          // 4 vocab rows per lane-group
    const float4* R0 = (const float4*)(Cr + (size_t)vb * 128);
    const float4* R1 = R0 + 32;
    const float4* R2 = R0 + 64;
    const float4* R3 = R0 + 96;
    float a0 = 0.f, a1 = 0.f, a2 = 0.f, a3 = 0.f;
    #pragma unroll 4
    for (int k = 0; k < 32; ++k) {
        float4 uu = us4[b][k];
        float4 c0 = R0[k], c1 = R1[k], c2 = R2[k], c3 = R3[k];
        a0 += c0.x * uu.x + c0.y * uu.y + c0.z * uu.z + c0.w * uu.w;
        a1 += c1.x * uu.x + c1.y * uu.y + c1.z * uu.z + c1.w * uu.w;
        a2 += c2.x * uu.x + c2.y * uu.y + c2.z * uu.z + c2.w * uu.w;
        a3 += c3.x * uu.x + c3.y * uu.y + c3.z * uu.z + c3.w * uu.w;
    }
    Pout[(size_t)(vb + 0) * 16 + b] = a0;
    Pout[(size_t)(vb + 1) * 16 + b] = a1;
    Pout[(size_t)(vb + 2) * 16 + b] = a2;
    Pout[(size_t)(vb + 3) * 16 + b] = a3;
}

// ---- scatter: chunk sc covers tokens [sc*512, sc*512+512) -----------------
__device__ __forceinline__ void scatter512(const int* __restrict__ story,
                                           float* __restrict__ ws,
                                           int offP, int offW, int offR,
                                           int sc, int tid) {
    #pragma unroll
    for (int it = 0; it < 2; ++it) {
        int tid0 = sc * 512 + it * 256 + tid;       // (b*4096 + m)*4 + s
        int b  = tid0 >> 14;                        // wave-uniform
        int st = story[tid0];
        float p = ws[offP + (size_t)st * 16 + b];
        p += __shfl_xor(p, 1, 64);                  // sum over s within the quad
        p += __shfl_xor(p, 2, 64);
        float e = __expf(p);                        // same e in all 4 quad lanes
        atomicAdd(&ws[offW + (size_t)st * 16 + b], e);
        float es = e;                               // count e once per quad
        es += __shfl_xor(es, 32, 64);
        es += __shfl_xor(es, 16, 64);
        es += __shfl_xor(es, 8, 64);
        es += __shfl_xor(es, 4, 64);
        if ((tid & 63) == 0)
            atomicAdd(&ws[offR + (sc & (NSLOT - 1)) * 16 + b], es);
    }
}

// ---- o-GEMV: uacc[b][d] += sum_v w[v][b]*C[v][d], rows [cb*64, cb*64+64) --
__device__ __forceinline__ void ogemm64(const float* __restrict__ Cr,
                                        float* __restrict__ ws,
                                        int offW, int offU, int cb, int tid) {
    int wave = tid >> 6, lane = tid & 63;
    int b0 = wave * 4;
    int v0 = cb * 64;
    float2 a0 = {0.f, 0.f}, a1 = {0.f, 0.f}, a2 = {0.f, 0.f}, a3 = {0.f, 0.f};
    for (int i = 0; i < 64; ++i) {
        int v = v0 + i;
        float2 c = ((const float2*)(Cr + (size_t)v * 128))[lane];
        float4 wv = *(const float4*)(ws + offW + (size_t)v * 16 + b0); // wave-uniform
        a0.x += wv.x * c.x; a0.y += wv.x * c.y;
        a1.x += wv.y * c.x; a1.y += wv.y * c.y;
        a2.x += wv.z * c.x; a2.y += wv.z * c.y;
        a3.x += wv.w * c.x; a3.y += wv.w * c.y;
    }
    float* U = ws + offU + (cb & (NSLOT - 1)) * 2048;
    int d = lane * 2;
    atomicAdd(&U[(b0 + 0) * 128 + d],     a0.x);
    atomicAdd(&U[(b0 + 0) * 128 + d + 1], a0.y);
    atomicAdd(&U[(b0 + 1) * 128 + d],     a1.x);
    atomicAdd(&U[(b0 + 1) * 128 + d + 1], a1.y);
    atomicAdd(&U[(b0 + 2) * 128 + d],     a2.x);
    atomicAdd(&U[(b0 + 2) * 128 + d + 1], a2.y);
    atomicAdd(&U[(b0 + 3) * 128 + d],     a3.x);
    atomicAdd(&U[(b0 + 3) * 128 + d + 1], a3.y);
}

// ---- build u (q + folded accumulators) into LDS; optionally emit u1 -------
__device__ __forceinline__ void build_u(const float* __restrict__ q,
                                        const float* __restrict__ ws,
                                        float4 (*us4)[33], float (*rr)[16],
                                        int which, int bid, int tid,
                                        float* __restrict__ u1_out) {
    if (tid < 16) {
        float r = 0.f;
        #pragma unroll
        for (int k = 0; k < NSLOT; ++k) r += ws[OFF_RSUM0 + k * 16 + tid];
        rr[0][tid] = 1.0f / r;
        if (which == 2) {
            float r1 = 0.f;
            #pragma unroll
            for (int k = 0; k < NSLOT; ++k) r1 += ws[OFF_RSUM1 + k * 16 + tid];
            rr[1][tid] = 1.0f / r1;
        }
    }
    __syncthreads();
    for (int t = tid; t < 512; t += 256) {
        int b = t >> 5;
        float4 u = ((const float4*)q)[t];
        float4 s = {0.f, 0.f, 0.f, 0.f};
        #pragma unroll
        for (int k = 0; k < NSLOT; ++k) {
            float4 a = ((const float4*)(ws + OFF_UACC0))[k * 512 + t];
            s.x += a.x; s.y += a.y; s.z += a.z; s.w += a.w;
        }
        float inv = rr[0][b];
        u.x += s.x * inv; u.y += s.y * inv; u.z += s.z * inv; u.w += s.w * inv;
        if (which == 2) {
            float4 s1 = {0.f, 0.f, 0.f, 0.f};
            #pragma unroll
            for (int k = 0; k < NSLOT; ++k) {
                float4 a = ((const float4*)(ws + OFF_UACC1))[k * 512 + t];
                s1.x += a.x; s1.y += a.y; s1.z += a.z; s1.w += a.w;
            }
            float inv1 = rr[1][b];
            u.x += s1.x * inv1; u.y += s1.y * inv1;
            u.z += s1.z * inv1; u.w += s1.w * inv1;
        }
        us4[t >> 5][t & 31] = u;
        if (u1_out && bid == 0)
            ((float4*)u1_out)[t] = u;
    }
    __syncthreads();
}

__device__ __forceinline__ void out512(const int* __restrict__ story,
                                       const float* __restrict__ ws,
                                       float* __restrict__ out, int sc, int tid) {
    #pragma unroll
    for (int it = 0; it < 2; ++it) {
        int tid0 = sc * 512 + it * 256 + tid;
        int b  = tid0 >> 14;
        int st = story[tid0];
        float p = ws[OFF_P2 + (size_t)st * 16 + b];
        p += __shfl_xor(p, 1, 64);
        p += __shfl_xor(p, 2, 64);
        if ((tid0 & 3) == 0) out[tid0 >> 2] = p;
    }
}

// ---- single cooperative kernel: 512 blocks (2/CU guaranteed), 7 syncs -----
__global__ __launch_bounds__(256, 2) void k_all(const int* __restrict__ story,
                                                const float* __restrict__ q,
                                                const float* __restrict__ C,
                                                float* __restrict__ ws,
                                                float* __restrict__ out,
                                                float* __restrict__ u1_out) {
    cg::grid_group grid = cg::this_grid();
    __shared__ float4 us4[16][33];
    __shared__ float  rr[2][16];
    int tid = threadIdx.x, bid = blockIdx.x;

    const float* C0 = C;
    const float* C1 = C + (size_t)VOCAB * 128;
    const float* C2 = C + (size_t)2 * VOCAB * 128;

    // phase 1: P0 = C0 . q
    if (bid < 500) {
        for (int t = tid; t < 512; t += 256)
            us4[t >> 5][t & 31] = ((const float4*)q)[t];
        __syncthreads();
        dense_gemv64(C0, ws + OFF_P0, us4, bid, tid);
    }
    grid.sync();

    // phase 2: scatter e0 -> w1, rsum0
    scatter512(story, ws, OFF_P0, OFF_W1, OFF_RSUM0, bid, tid);
    grid.sync();

    // phase 3: uacc0 = C1^T w1
    if (bid < 500) ogemm64(C1, ws, OFF_W1, OFF_UACC0, bid, tid);
    grid.sync();

    // phase 4: u1 = q + o0/r0; P1 = C1 . u1; block 0 emits u1
    if (bid < 500) {
        build_u(q, ws, us4, rr, 1, bid, tid, u1_out);
        dense_gemv64(C1, ws + OFF_P1, us4, bid, tid);
    }
    grid.sync();

    // phase 5: scatter e1 -> w2, rsum1
    scatter512(story, ws, OFF_P1, OFF_W2, OFF_RSUM1, bid, tid);
    grid.sync();

    // phase 6: uacc1 = C2^T w2
    if (bid < 500) ogemm64(C2, ws, OFF_W2, OFF_UACC1, bid, tid);
    grid.sync();

    // phase 7: u2 = q + o0/r0 + o1/r1; P2 = C2 . u2
    if (bid < 500) {
        build_u(q, ws, us4, rr, 2, bid, tid, nullptr);
        dense_gemv64(C2, ws + OFF_P2, us4, bid, tid);
    }
    grid.sync();

    // phase 8: out[b,m] = sum_s P2[st,b]
    out512(story, ws, out, bid, tid);
}

// ---- fallback path: 8 plain launches (round-1 semantics, known-correct) ---
__global__ __launch_bounds__(256) void k_fb_p0(const float* __restrict__ C0,
                                               const float* __restrict__ q,
                                               float* __restrict__ ws) {
    __shared__ float4 us4[16][33];
    int tid = threadIdx.x;
    for (int t = tid; t < 512; t += 256)
        us4[t >> 5][t & 31] = ((const float4*)q)[t];
    __syncthreads();
    dense_gemv64(C0, ws + OFF_P0, us4, blockIdx.x, tid);
}
__global__ __launch_bounds__(256) void k_fb_scatter(const int* __restrict__ story,
                                                    float* __restrict__ ws,
                                                    int offP, int offW, int offR) {
    scatter512(story, ws, offP, offW, offR, blockIdx.x, threadIdx.x);
}
__global__ __launch_bounds__(256) void k_fb_ogemm(const float* __restrict__ Cr,
                                                  float* __restrict__ ws,
                                                  int offW, int offU) {
    ogemm64(Cr, ws, offW, offU, blockIdx.x, threadIdx.x);
}
__global__ __launch_bounds__(256) void k_fb_p1(const float* __restrict__ C1,
                                               const float* __restrict__ q,
                                               float* __restrict__ ws,
                                               float* __restrict__ u1_out) {
    __shared__ float4 us4[16][33];
    __shared__ float  rr[2][16];
    build_u(q, ws, us4, rr, 1, blockIdx.x, threadIdx.x, u1_out);
    dense_gemv64(C1, ws + OFF_P1, us4, blockIdx.x, threadIdx.x);
}
__global__ __launch_bounds__(256) void k_fb_p2(const float* __restrict__ C2,
                                               const float* __restrict__ q,
                                               float* __restrict__ ws) {
    __shared__ float4 us4[16][33];
    __shared__ float  rr[2][16];
    build_u(q, ws, us4, rr, 2, blockIdx.x, threadIdx.x, nullptr);
    dense_gemv64(C2, ws + OFF_P2, us4, blockIdx.x, threadIdx.x);
}
__global__ __launch_bounds__(256) void k_fb_out(const int* __restrict__ story,
                                                const float* __restrict__ ws,
                                                float* __restrict__ out) {
    out512(story, ws, out, blockIdx.x, threadIdx.x);
}

extern "C" void kernel_launch(void* const* d_in, const int* in_sizes, int n_in,
                              void* d_out, int out_size, void* d_ws, size_t ws_size,
                              hipStream_t stream) {
    const int*   story = (const int*)d_in[0];
    const float* q     = (const float*)d_in[1];
    const float* C     = (const float*)d_in[2];
    float* out    = (float*)d_out;              // [B*M logits][B*D u1]
    float* ws     = (float*)d_ws;
    float* u1_out = out + 16 * 4096;
    const float* C0 = C;
    const float* C1 = C + (size_t)VOCAB * 128;
    const float* C2 = C + (size_t)2 * VOCAB * 128;

    void* args[] = { (void*)&story, (void*)&q, (void*)&C,
                     (void*)&ws, (void*)&out, (void*)&u1_out };
    hipError_t e = hipLaunchCooperativeKernel((void*)k_all, dim3(512), dim3(256),
                                              args, 0, stream);
    if (e != hipSuccess) {
        (void)hipGetLastError();                 // clear sticky error
        k_fb_p0<<<500, 256, 0, stream>>>(C0, q, ws);
        k_fb_scatter<<<512, 256, 0, stream>>>(story, ws, OFF_P0, OFF_W1, OFF_RSUM0);
        k_fb_ogemm<<<500, 256, 0, stream>>>(C1, ws, OFF_W1, OFF_UACC0);
        k_fb_p1<<<500, 256, 0, stream>>>(C1, q, ws, u1_out);
        k_fb_scatter<<<512, 256, 0, stream>>>(story, ws, OFF_P1, OFF_W2, OFF_RSUM1);
        k_fb_ogemm<<<500, 256, 0, stream>>>(C2, ws, OFF_W2, OFF_UACC1);
        k_fb_p2<<<500, 256, 0, stream>>>(C2, q, ws);
        k_fb_out<<<512, 256, 0, stream>>>(story, ws, out);
    }
}

// Round 4
// 199.835 us; speedup vs baseline: 2.9393x; 2.9393x over previous
//
#include <hip/hip_runtime.h>

typedef unsigned int uint;

#define VOCAB 32000
#define NSLOT 8

// ws float offsets. Poison 0xAA = -3.03e-13f is numerically zero for all
// accumulations (uacc/rsum slots accumulate straight onto it). P tables are
// fully overwritten by k_prep.
#define OFF_UACC0 0          // NSLOT x 16 x 128
#define OFF_RSUM0 16384      // NSLOT x 16
#define OFF_UACC1 16512
#define OFF_RSUM1 32896      // ends 33024
#define OFF_P0    33024      // P0[v*16+b]  = C0[v].q[b]
#define OFF_P1Q   545024     // P1q[v*16+b] = C1[v].q[b]
#define OFF_P2Q   1057024    // P2q[v*16+b] = C2[v].q[b]; ends 1569024 (6.3 MB)

// ---- dense pass: chunk cb covers vocab rows [cb*64, cb*64+64) -------------
__device__ __forceinline__ void dense_gemv64(const float* __restrict__ Cr,
                                             float* __restrict__ Pout,
                                             const float4 (*us4)[33],
                                             int cb, int tid) {
    int wave = tid >> 6, lane = tid & 63;
    int b  = lane & 15;
    int rl = lane >> 4;
    int vb = cb * 64 + wave * 16 + rl * 4;          // 4 vocab rows per lane-group
    const float4* R0 = (const float4*)(Cr + (size_t)vb * 128);
    const float4* R1 = R0 + 32;
    const float4* R2 = R0 + 64;
    const float4* R3 = R0 + 96;
    float a0 = 0.f, a1 = 0.f, a2 = 0.f, a3 = 0.f;
    #pragma unroll 4
    for (int k = 0; k < 32; ++k) {
        float4 uu = us4[b][k];
        float4 c0 = R0[k], c1 = R1[k], c2 = R2[k], c3 = R3[k];
        a0 += c0.x * uu.x + c0.y * uu.y + c0.z * uu.z + c0.w * uu.w;
        a1 += c1.x * uu.x + c1.y * uu.y + c1.z * uu.z + c1.w * uu.w;
        a2 += c2.x * uu.x + c2.y * uu.y + c2.z * uu.z + c2.w * uu.w;
        a3 += c3.x * uu.x + c3.y * uu.y + c3.z * uu.z + c3.w * uu.w;
    }
    Pout[(size_t)(vb + 0) * 16 + b] = a0;
    Pout[(size_t)(vb + 1) * 16 + b] = a1;
    Pout[(size_t)(vb + 2) * 16 + b] = a2;
    Pout[(size_t)(vb + 3) * 16 + b] = a3;
}

// ---- D1: all three q-projections (no dependencies): 1500 blocks -----------
__global__ __launch_bounds__(256) void k_prep(const float* __restrict__ C,
                                              const float* __restrict__ q,
                                              float* __restrict__ ws) {
    __shared__ float4 us4[16][33];
    int tid = threadIdx.x, bid = blockIdx.x;
    for (int t = tid; t < 512; t += 256)
        us4[t >> 5][t & 31] = ((const float4*)q)[t];
    __syncthreads();
    int tbl = bid / 500, cb = bid - tbl * 500;      // table 0,1,2 x 500 chunks
    const float* Cr = C + (size_t)tbl * VOCAB * 128;
    float* Pout = ws + OFF_P0 + (size_t)tbl * (VOCAB * 16);
    dense_gemv64(Cr, Pout, us4, cb, tid);
}

#define XRED(f) { f += __shfl_xor(f, 8, 64); f += __shfl_xor(f, 16, 64); \
                  f += __shfl_xor(f, 32, 64); }
#define XRED4(v) XRED(v.x) XRED(v.y) XRED(v.z) XRED(v.w)

// ---- D2/D3/D4: token hop kernels. 1024 blocks x 256 thr; block owns 64
// (b,m) pairs of a single b (bid>>6 = b, 64 blocks per b). Wave layout:
// half = lane>>5 -> one (b,m) per 32-lane half; sg = (lane>>3)&3 -> story
// slot s; li = lane&7 -> d-chunk (float4 li+8c covers d=(li+8c)*4..+4).
// HOP0: logit from P0 gather; o0 += e*C1[st] (register acc -> LDS -> slots).
// HOP1: logit = P1q[st] + C1[st].(o0/r0); o1 += e*C2[st]; emits u1.
// HOP2: out = sum_s P2q[st] + C2[st].(o0/r0 + o1/r1).
template <int HOP>
__global__ __launch_bounds__(256) void k_hop(const int4* __restrict__ story4,
                                             const float* __restrict__ q,
                                             const float* __restrict__ C,
                                             float* __restrict__ ws,
                                             float* __restrict__ outp) {
    __shared__ float4 obuf4[32];                    // block-local o partial
    __shared__ float4 ucorr4[32];                   // folded correction vector
    __shared__ float  rs;
    float* obuf  = (float*)obuf4;
    float* ucorr = (float*)ucorr4;

    int tid = threadIdx.x, bid = blockIdx.x;
    int lane = tid & 63, wave = tid >> 6;
    int half = lane >> 5, sg = (lane >> 3) & 3, li = lane & 7;
    int b = bid >> 6;

    if (tid < 128) obuf[tid] = 0.f;
    if (tid == 0) rs = 0.f;
    if constexpr (HOP >= 1) {
        if (tid < 128) {
            float s0 = 0.f, r0 = 0.f;
            #pragma unroll
            for (int k = 0; k < NSLOT; ++k) s0 += ws[OFF_UACC0 + k * 2048 + b * 128 + tid];
            #pragma unroll
            for (int k = 0; k < NSLOT; ++k) r0 += ws[OFF_RSUM0 + k * 16 + b];
            float v = s0 / r0;
            if constexpr (HOP == 2) {
                float s1 = 0.f, r1 = 0.f;
                #pragma unroll
                for (int k = 0; k < NSLOT; ++k) s1 += ws[OFF_UACC1 + k * 2048 + b * 128 + tid];
                #pragma unroll
                for (int k = 0; k < NSLOT; ++k) r1 += ws[OFF_RSUM1 + k * 16 + b];
                v += s1 / r1;
            }
            ucorr[tid] = v;
        }
    }
    __syncthreads();

    if constexpr (HOP == 1) {                       // u1 = q + o0/r0
        if ((bid & 63) == 0 && tid < 128)
            outp[b * 128 + tid] = q[b * 128 + tid] + ucorr[tid];
    }

    const float* Pq = ws + (HOP == 0 ? OFF_P0 : (HOP == 1 ? OFF_P1Q : OFF_P2Q));
    const float* Ccorr = C + (size_t)(HOP == 1 ? 1 : 2) * VOCAB * 128; // HOP>=1
    const float* Cacc  = C + (size_t)(HOP == 0 ? 1 : 2) * VOCAB * 128; // HOP<=1

    float4 acc0 = {0,0,0,0}, acc1 = {0,0,0,0}, acc2 = {0,0,0,0}, acc3 = {0,0,0,0};
    float er = 0.f;

    #pragma unroll 2
    for (int it = 0; it < 8; ++it) {
        int bm = (bid << 6) + (it << 3) + (wave << 1) + half;
        int4 st4 = story4[bm];
        int st = (sg == 0) ? st4.x : (sg == 1) ? st4.y : (sg == 2) ? st4.z : st4.w;
        float t = Pq[(size_t)st * 16 + b];          // broadcast within s-group
        float z;
        if constexpr (HOP >= 1) {
            const float4* R = (const float4*)(Ccorr + (size_t)st * 128);
            float4 c0 = R[li], c1 = R[li + 8], c2 = R[li + 16], c3 = R[li + 24];
            float4 u0 = ucorr4[li],      u1v = ucorr4[li + 8],
                   u2v = ucorr4[li + 16], u3v = ucorr4[li + 24];
            float dp = c0.x*u0.x + c0.y*u0.y + c0.z*u0.z + c0.w*u0.w
                     + c1.x*u1v.x + c1.y*u1v.y + c1.z*u1v.z + c1.w*u1v.w
                     + c2.x*u2v.x + c2.y*u2v.y + c2.z*u2v.z + c2.w*u2v.w
                     + c3.x*u3v.x + c3.y*u3v.y + c3.z*u3v.z + c3.w*u3v.w;
            z = dp + ((li == 0) ? t : 0.f);
        } else {
            z = (li == 0) ? t : 0.f;
        }
        z += __shfl_xor(z, 1, 64);                  // sum over li (8 lanes)
        z += __shfl_xor(z, 2, 64);
        z += __shfl_xor(z, 4, 64);
        z += __shfl_xor(z, 8, 64);                  // sum over sg (4 slots)
        z += __shfl_xor(z, 16, 64);                 // all 32 lanes: logit
        if constexpr (HOP == 2) {
            if ((lane & 31) == 0) outp[bm] = z;     // pre-softmax logits
        } else {
            float e = __expf(z);
            if ((lane & 31) == 0) er += e;          // count once per (b,m)
            const float4* A = (const float4*)(Cacc + (size_t)st * 128);
            float4 a0 = A[li], a1 = A[li + 8], a2 = A[li + 16], a3 = A[li + 24];
            acc0.x = fmaf(e, a0.x, acc0.x); acc0.y = fmaf(e, a0.y, acc0.y);
            acc0.z = fmaf(e, a0.z, acc0.z); acc0.w = fmaf(e, a0.w, acc0.w);
            acc1.x = fmaf(e, a1.x, acc1.x); acc1.y = fmaf(e, a1.y, acc1.y);
            acc1.z = fmaf(e, a1.z, acc1.z); acc1.w = fmaf(e, a1.w, acc1.w);
            acc2.x = fmaf(e, a2.x, acc2.x); acc2.y = fmaf(e, a2.y, acc2.y);
            acc2.z = fmaf(e, a2.z, acc2.z); acc2.w = fmaf(e, a2.w, acc2.w);
            acc3.x = fmaf(e, a3.x, acc3.x); acc3.y = fmaf(e, a3.y, acc3.y);
            acc3.z = fmaf(e, a3.z, acc3.z); acc3.w = fmaf(e, a3.w, acc3.w);
        }
    }

    if constexpr (HOP <= 1) {
        // reduce acc over sg (xor 8,16) and half (xor 32); li preserved
        XRED4(acc0) XRED4(acc1) XRED4(acc2) XRED4(acc3)
        er += __shfl_xor(er, 32, 64);
        if (lane < 8) {                             // li = lane; 8 active lanes
            atomicAdd(&obuf[(li +  0) * 4 + 0], acc0.x);
            atomicAdd(&obuf[(li +  0) * 4 + 1], acc0.y);
            atomicAdd(&obuf[(li +  0) * 4 + 2], acc0.z);
            atomicAdd(&obuf[(li +  0) * 4 + 3], acc0.w);
            atomicAdd(&obuf[(li +  8) * 4 + 0], acc1.x);
            atomicAdd(&obuf[(li +  8) * 4 + 1], acc1.y);
            atomicAdd(&obuf[(li +  8) * 4 + 2], acc1.z);
            atomicAdd(&obuf[(li +  8) * 4 + 3], acc1.w);
            atomicAdd(&obuf[(li + 16) * 4 + 0], acc2.x);
            atomicAdd(&obuf[(li + 16) * 4 + 1], acc2.y);
            atomicAdd(&obuf[(li + 16) * 4 + 2], acc2.z);
            atomicAdd(&obuf[(li + 16) * 4 + 3], acc2.w);
            atomicAdd(&obuf[(li + 24) * 4 + 0], acc3.x);
            atomicAdd(&obuf[(li + 24) * 4 + 1], acc3.y);
            atomicAdd(&obuf[(li + 24) * 4 + 2], acc3.z);
            atomicAdd(&obuf[(li + 24) * 4 + 3], acc3.w);
        }
        if (lane == 0) atomicAdd(&rs, er);
        __syncthreads();
        if (wave == 0) {                            // block partial -> slots
            int slot = bid & (NSLOT - 1);
            float* U = ws + (HOP == 0 ? OFF_UACC0 : OFF_UACC1)
                          + slot * 2048 + b * 128;
            atomicAdd(&U[lane * 2],     obuf[lane * 2]);
            atomicAdd(&U[lane * 2 + 1], obuf[lane * 2 + 1]);
            if (lane == 0)
                atomicAdd(&ws[(HOP == 0 ? OFF_RSUM0 : OFF_RSUM1)
                              + slot * 16 + b], rs);
        }
    }
}

extern "C" void kernel_launch(void* const* d_in, const int* in_sizes, int n_in,
                              void* d_out, int out_size, void* d_ws, size_t ws_size,
                              hipStream_t stream) {
    const int4*  story4 = (const int4*)d_in[0];
    const float* q      = (const float*)d_in[1];
    const float* C      = (const float*)d_in[2];
    float* out    = (float*)d_out;              // [B*M logits][B*D u1]
    float* ws     = (float*)d_ws;
    float* u1_out = out + 16 * 4096;

    k_prep<<<1500, 256, 0, stream>>>(C, q, ws);
    k_hop<0><<<1024, 256, 0, stream>>>(story4, q, C, ws, nullptr);
    k_hop<1><<<1024, 256, 0, stream>>>(story4, q, C, ws, u1_out);
    k_hop<2><<<1024, 256, 0, stream>>>(story4, q, C, ws, out);
}

// Round 5
// 175.947 us; speedup vs baseline: 3.3383x; 1.1358x over previous
//
#include <hip/hip_runtime.h>

typedef unsigned int uint;

#define VOCAB 32000
#define NSLOT 8

// ws float offsets. Poison 0xAA = -3.03e-13f is numerically zero for all
// accumulations (uacc/rsum slots accumulate straight onto it). P tables and
// CB tables are fully overwritten by k_prep.
#define OFF_UACC0 0          // NSLOT x 16 x 128
#define OFF_RSUM0 16384      // NSLOT x 16
#define OFF_UACC1 16512
#define OFF_RSUM1 32896      // ends 33024
#define OFF_P0    33024      // P0[v*16+b]  = C0[v].q[b]
#define OFF_P1Q   545024     // P1q[v*16+b] = C1[v].q[b]
#define OFF_P2Q   1057024    // P2q[v*16+b] = C2[v].q[b]
#define OFF_CB1   1569024    // C1 as bf16 rows: VOCAB*64 uints
#define OFF_CB2   3617024    // C2 as bf16 rows; ends 5665024 (~22.7 MB)

// pack two fp32 -> (lo,hi) bf16 pair with RNE (round-0 verified)
__device__ __forceinline__ uint f2bf2(float lo, float hi) {
    uint a = __float_as_uint(lo), b = __float_as_uint(hi);
    a = (a + 0x7FFFu + ((a >> 16) & 1u)) >> 16;
    b = (b + 0x7FFFu + ((b >> 16) & 1u)) & 0xFFFF0000u;
    return a | b;
}
__device__ __forceinline__ float bflo(uint u) { return __uint_as_float(u << 16); }
__device__ __forceinline__ float bfhi(uint u) { return __uint_as_float(u & 0xFFFF0000u); }

// dot of one bf16 uint4 (8 dims) against two float4 (8 dims)
__device__ __forceinline__ float bdot8(uint4 c, float4 uA, float4 uB) {
    return bflo(c.x)*uA.x + bfhi(c.x)*uA.y + bflo(c.y)*uA.z + bfhi(c.y)*uA.w
         + bflo(c.z)*uB.x + bfhi(c.z)*uB.y + bflo(c.w)*uB.z + bfhi(c.w)*uB.w;
}
// acc += e * (bf16 uint4, 8 dims) into two float4 accumulators
__device__ __forceinline__ void bacc8(uint4 a, float e, float4& A, float4& B) {
    A.x = fmaf(e, bflo(a.x), A.x); A.y = fmaf(e, bfhi(a.x), A.y);
    A.z = fmaf(e, bflo(a.y), A.z); A.w = fmaf(e, bfhi(a.y), A.w);
    B.x = fmaf(e, bflo(a.z), B.x); B.y = fmaf(e, bfhi(a.z), B.y);
    B.z = fmaf(e, bflo(a.w), B.z); B.w = fmaf(e, bfhi(a.w), B.w);
}

// ---- dense pass: chunk cb covers vocab rows [cb*64, cb*64+64) -------------
__device__ __forceinline__ void dense_gemv64(const float* __restrict__ Cr,
                                             float* __restrict__ Pout,
                                             const float4 (*us4)[33],
                                             int cb, int tid) {
    int wave = tid >> 6, lane = tid & 63;
    int b  = lane & 15;
    int rl = lane >> 4;
    int vb = cb * 64 + wave * 16 + rl * 4;          // 4 vocab rows per lane-group
    const float4* R0 = (const float4*)(Cr + (size_t)vb * 128);
    const float4* R1 = R0 + 32;
    const float4* R2 = R0 + 64;
    const float4* R3 = R0 + 96;
    float a0 = 0.f, a1 = 0.f, a2 = 0.f, a3 = 0.f;
    #pragma unroll 4
    for (int k = 0; k < 32; ++k) {
        float4 uu = us4[b][k];
        float4 c0 = R0[k], c1 = R1[k], c2 = R2[k], c3 = R3[k];
        a0 += c0.x * uu.x + c0.y * uu.y + c0.z * uu.z + c0.w * uu.w;
        a1 += c1.x * uu.x + c1.y * uu.y + c1.z * uu.z + c1.w * uu.w;
        a2 += c2.x * uu.x + c2.y * uu.y + c2.z * uu.z + c2.w * uu.w;
        a3 += c3.x * uu.x + c3.y * uu.y + c3.z * uu.z + c3.w * uu.w;
    }
    Pout[(size_t)(vb + 0) * 16 + b] = a0;
    Pout[(size_t)(vb + 1) * 16 + b] = a1;
    Pout[(size_t)(vb + 2) * 16 + b] = a2;
    Pout[(size_t)(vb + 3) * 16 + b] = a3;
}

// ---- D1: three q-projections + C1/C2 -> bf16 conversion (no deps) ---------
__global__ __launch_bounds__(256) void k_prep(const float* __restrict__ C,
                                              const float* __restrict__ q,
                                              float* __restrict__ ws) {
    int tid = threadIdx.x, bid = blockIdx.x;
    if (bid < 1500) {
        __shared__ float4 us4[16][33];
        for (int t = tid; t < 512; t += 256)
            us4[t >> 5][t & 31] = ((const float4*)q)[t];
        __syncthreads();
        int tbl = bid / 500, cb = bid - tbl * 500;  // table 0,1,2 x 500 chunks
        const float* Cr = C + (size_t)tbl * VOCAB * 128;
        float* Pout = ws + OFF_P0 + (size_t)tbl * (VOCAB * 16);
        dense_gemv64(Cr, Pout, us4, cb, tid);
    } else {
        int g0 = (bid - 1500) * 256 + tid;          // 262144 threads
        const float4* C1 = (const float4*)(C + (size_t)VOCAB * 128);
        const float4* C2 = (const float4*)(C + (size_t)2 * VOCAB * 128);
        uint2* D1 = (uint2*)(ws + OFF_CB1);
        uint2* D2 = (uint2*)(ws + OFF_CB2);
        for (int g = g0; g < VOCAB * 32; g += 262144) {
            float4 c1 = C1[g], c2 = C2[g];
            uint2 o1; o1.x = f2bf2(c1.x, c1.y); o1.y = f2bf2(c1.z, c1.w);
            uint2 o2; o2.x = f2bf2(c2.x, c2.y); o2.y = f2bf2(c2.z, c2.w);
            D1[g] = o1; D2[g] = o2;
        }
    }
}

#define XRED(f) { f += __shfl_xor(f, 8, 64); f += __shfl_xor(f, 16, 64); \
                  f += __shfl_xor(f, 32, 64); }
#define XRED4(v) XRED(v.x) XRED(v.y) XRED(v.z) XRED(v.w)

// ---- D2/D3/D4: token hop kernels. 2048 blocks x 256 thr; block owns 32
// (b,m) of a single b (b = bid>>7). Wave: half = lane>>5 (one bm per half),
// sg = (lane>>3)&3 (story slot), li = lane&7 (dims [8li,8li+8) + [64+8li,+8)).
// Gathered C rows are bf16 (256 B = 4 cache lines). Logit P tables fp32.
// HOP0: logit = sum_s P0[st]; o0 += e*CB1[st].
// HOP1: logit = sum_s (P1q[st] + CB1[st].ucorr); o1 += e*CB2[st]; emits u1.
// HOP2: out  = sum_s (P2q[st] + CB2[st].ucorr).
template <int HOP>
__global__ __launch_bounds__(256) void k_hop(const int4* __restrict__ story4,
                                             const float* __restrict__ q,
                                             float* __restrict__ ws,
                                             float* __restrict__ outp) {
    __shared__ float4 obuf4[32];                    // block-local o partial
    __shared__ float4 ucorr4[32];                   // folded correction vector
    __shared__ float  rs;
    float* obuf  = (float*)obuf4;
    float* ucorr = (float*)ucorr4;

    int tid = threadIdx.x, bid = blockIdx.x;
    int lane = tid & 63, wave = tid >> 6;
    int half = lane >> 5, sg = (lane >> 3) & 3, li = lane & 7;
    int b = bid >> 7;

    if (tid < 128) obuf[tid] = 0.f;
    if (tid == 0) rs = 0.f;
    if constexpr (HOP >= 1) {
        if (tid < 128) {
            float s0 = 0.f, r0 = 0.f;
            #pragma unroll
            for (int k = 0; k < NSLOT; ++k) s0 += ws[OFF_UACC0 + k * 2048 + b * 128 + tid];
            #pragma unroll
            for (int k = 0; k < NSLOT; ++k) r0 += ws[OFF_RSUM0 + k * 16 + b];
            float v = s0 / r0;
            if constexpr (HOP == 2) {
                float s1 = 0.f, r1 = 0.f;
                #pragma unroll
                for (int k = 0; k < NSLOT; ++k) s1 += ws[OFF_UACC1 + k * 2048 + b * 128 + tid];
                #pragma unroll
                for (int k = 0; k < NSLOT; ++k) r1 += ws[OFF_RSUM1 + k * 16 + b];
                v += s1 / r1;
            }
            ucorr[tid] = v;
        }
    }
    __syncthreads();

    if constexpr (HOP == 1) {                       // u1 = q + o0/r0
        if ((bid & 127) == 0 && tid < 128)
            outp[b * 128 + tid] = q[b * 128 + tid] + ucorr[tid];
    }

    const float* Pq = ws + (HOP == 0 ? OFF_P0 : (HOP == 1 ? OFF_P1Q : OFF_P2Q));
    const uint4* CBc4 = (const uint4*)(ws + (HOP == 1 ? OFF_CB1 : OFF_CB2)); // HOP>=1
    const uint4* CBa4 = (const uint4*)(ws + (HOP == 0 ? OFF_CB1 : OFF_CB2)); // HOP<=1

    // ucorr slices for this lane (LDS-resident, re-read per token is cheap)
    float4 uA = {0,0,0,0}, uB = {0,0,0,0}, uC = {0,0,0,0}, uD = {0,0,0,0};
    if constexpr (HOP >= 1) {
        uA = ucorr4[2 * li];     uB = ucorr4[2 * li + 1];
        uC = ucorr4[16 + 2 * li]; uD = ucorr4[16 + 2 * li + 1];
    }

    float4 acc0 = {0,0,0,0}, acc1 = {0,0,0,0}, acc2 = {0,0,0,0}, acc3 = {0,0,0,0};
    float er = 0.f;

    #pragma unroll 2
    for (int it = 0; it < 4; ++it) {
        int bm = (bid << 5) + (it << 3) + (wave << 1) + half;
        int4 st4 = story4[bm];
        int st = (sg == 0) ? st4.x : (sg == 1) ? st4.y : (sg == 2) ? st4.z : st4.w;
        float t = Pq[(size_t)st * 16 + b];          // broadcast within s-group
        float z;
        if constexpr (HOP >= 1) {
            uint4 c0 = CBc4[(size_t)st * 16 + li];
            uint4 c1 = CBc4[(size_t)st * 16 + 8 + li];
            float dp = bdot8(c0, uA, uB) + bdot8(c1, uC, uD);
            z = dp + ((li == 0) ? t : 0.f);
        } else {
            z = (li == 0) ? t : 0.f;
        }
        z += __shfl_xor(z, 1, 64);                  // sum over li (8 lanes)
        z += __shfl_xor(z, 2, 64);
        z += __shfl_xor(z, 4, 64);
        z += __shfl_xor(z, 8, 64);                  // sum over sg (4 slots)
        z += __shfl_xor(z, 16, 64);                 // all 32 lanes: logit
        if constexpr (HOP == 2) {
            if ((lane & 31) == 0) outp[bm] = z;     // pre-softmax logits
        } else {
            float e = __expf(z);
            if ((lane & 31) == 0) er += e;          // count once per (b,m)
            uint4 a0 = CBa4[(size_t)st * 16 + li];
            uint4 a1 = CBa4[(size_t)st * 16 + 8 + li];
            bacc8(a0, e, acc0, acc1);
            bacc8(a1, e, acc2, acc3);
        }
    }

    if constexpr (HOP <= 1) {
        // reduce acc over sg (xor 8,16) and half (xor 32); li preserved
        XRED4(acc0) XRED4(acc1) XRED4(acc2) XRED4(acc3)
        er += __shfl_xor(er, 32, 64);
        if (lane < 8) {                             // li = lane; 8 active lanes
            atomicAdd(&obuf[8 * li + 0], acc0.x);
            atomicAdd(&obuf[8 * li + 1], acc0.y);
            atomicAdd(&obuf[8 * li + 2], acc0.z);
            atomicAdd(&obuf[8 * li + 3], acc0.w);
            atomicAdd(&obuf[8 * li + 4], acc1.x);
            atomicAdd(&obuf[8 * li + 5], acc1.y);
            atomicAdd(&obuf[8 * li + 6], acc1.z);
            atomicAdd(&obuf[8 * li + 7], acc1.w);
            atomicAdd(&obuf[64 + 8 * li + 0], acc2.x);
            atomicAdd(&obuf[64 + 8 * li + 1], acc2.y);
            atomicAdd(&obuf[64 + 8 * li + 2], acc2.z);
            atomicAdd(&obuf[64 + 8 * li + 3], acc2.w);
            atomicAdd(&obuf[64 + 8 * li + 4], acc3.x);
            atomicAdd(&obuf[64 + 8 * li + 5], acc3.y);
            atomicAdd(&obuf[64 + 8 * li + 6], acc3.z);
            atomicAdd(&obuf[64 + 8 * li + 7], acc3.w);
        }
        if (lane == 0) atomicAdd(&rs, er);
        __syncthreads();
        if (wave == 0) {                            // block partial -> slots
            int slot = bid & (NSLOT - 1);
            float* U = ws + (HOP == 0 ? OFF_UACC0 : OFF_UACC1)
                          + slot * 2048 + b * 128;
            atomicAdd(&U[lane * 2],     obuf[lane * 2]);
            atomicAdd(&U[lane * 2 + 1], obuf[lane * 2 + 1]);
            if (lane == 0)
                atomicAdd(&ws[(HOP == 0 ? OFF_RSUM0 : OFF_RSUM1)
                              + slot * 16 + b], rs);
        }
    }
}

extern "C" void kernel_launch(void* const* d_in, const int* in_sizes, int n_in,
                              void* d_out, int out_size, void* d_ws, size_t ws_size,
                              hipStream_t stream) {
    const int4*  story4 = (const int4*)d_in[0];
    const float* q      = (const float*)d_in[1];
    const float* C      = (const float*)d_in[2];
    float* out    = (float*)d_out;              // [B*M logits][B*D u1]
    float* ws     = (float*)d_ws;
    float* u1_out = out + 16 * 4096;

    k_prep<<<2524, 256, 0, stream>>>(C, q, ws);
    k_hop<0><<<2048, 256, 0, stream>>>(story4, q, ws, nullptr);
    k_hop<1><<<2048, 256, 0, stream>>>(story4, q, ws, u1_out);
    k_hop<2><<<2048, 256, 0, stream>>>(story4, q, ws, out);
}